// Round 1
// baseline (172.177 us; speedup 1.0000x reference)
//
#include <hip/hip_runtime.h>
#include <math.h>

// RandomMicEQ: cascade of 3 biquads (equalizer -> lowpass -> highpass), each
// stage's output clamped to [-1,1] before feeding the next stage. The IIR
// recursion inside each stage uses UNCLAMPED history (matches jax reference:
// clip is applied after the scan, but the scan carry is unclamped).
//
// Parallelization: overlap-save chunking. Each thread computes an L-sample
// output chunk by running the fused cascade from zero state starting W
// samples earlier; the transient decays as r_max^W (r_max = 0.9702, HP pole)
// -> ~2e-7 at W=512, far below the 7.7e-3 absmax threshold.

struct BQ { float b0, b1, b2, a1, a2; };

#define L_CHUNK 256
#define W_WARM  512

__global__ __launch_bounds__(64) void biquad3_kernel(
    const float* __restrict__ x, float* __restrict__ out,
    int T, int chunksPerRow, int nThreads,
    BQ F1, BQ F2, BQ F3)
{
    int tid = blockIdx.x * blockDim.x + threadIdx.x;
    if (tid >= nThreads) return;
    int row = tid / chunksPerRow;
    int c   = tid - row * chunksPerRow;

    int t0    = c * L_CHUNK;          // first output sample of this chunk
    int begin = t0 - W_WARM;          // warm-up start (zero initial state)
    if (begin < 0) begin = 0;
    int end   = t0 + L_CHUNK;
    if (end > T) end = T;
    // begin/end/t0 are all multiples of 4; row base is 16B aligned
    // (441000*4B = 1764000B, multiple of 16).

    const float* xr = x   + (long long)row * T;
    float*       yr = out + (long long)row * T;

    // filter states (direct-form I per stage)
    float x1=0.f, x2=0.f, y1=0.f, y2=0.f;   // stage 1 (EQ)
    float u1=0.f, u2=0.f, v1=0.f, v2=0.f;   // stage 2 (LP)
    float p1=0.f, p2=0.f, q1=0.f, q2=0.f;   // stage 3 (HP)

    auto step = [&](float xt) -> float {
        float f = F1.b0*xt + F1.b1*x1 + F1.b2*x2;
        float y = f - F1.a1*y1 - F1.a2*y2;
        x2 = x1; x1 = xt; y2 = y1; y1 = y;
        float u = fminf(fmaxf(y, -1.f), 1.f);

        float g = F2.b0*u + F2.b1*u1 + F2.b2*u2;
        float v = g - F2.a1*v1 - F2.a2*v2;
        u2 = u1; u1 = u; v2 = v1; v1 = v;
        float p = fminf(fmaxf(v, -1.f), 1.f);

        float h = F3.b0*p + F3.b1*p1 + F3.b2*p2;
        float q = h - F3.a1*q1 - F3.a2*q2;
        p2 = p1; p1 = p; q2 = q1; q1 = q;
        return fminf(fmaxf(q, -1.f), 1.f);
    };

    // 4-wide streaming with one-slot prefetch to hide load latency
    float4 cur = *(const float4*)(xr + begin);
    for (int t = begin; t < end; t += 4) {
        float4 nxt = cur;
        if (t + 4 < end) nxt = *(const float4*)(xr + t + 4);
        float o0 = step(cur.x);
        float o1 = step(cur.y);
        float o2 = step(cur.z);
        float o3 = step(cur.w);
        if (t >= t0) {
            *(float4*)(yr + t) = make_float4(o0, o1, o2, o3);
        }
        cur = nxt;
    }
}

// ---- host-side coefficient computation (double, matching numpy refs) ----

static BQ make_eq(double f0, double gain_db, double Q) {
    const double SR = 44100.0;
    double w0 = 2.0 * M_PI * f0 / SR;
    double alpha = sin(w0) / (2.0 * Q);
    double A = pow(10.0, gain_db / 40.0);
    double b0 = 1.0 + alpha * A, b1 = -2.0 * cos(w0), b2 = 1.0 - alpha * A;
    double a0 = 1.0 + alpha / A, a1 = -2.0 * cos(w0), a2 = 1.0 - alpha / A;
    BQ r;
    r.b0 = (float)(b0 / a0); r.b1 = (float)(b1 / a0); r.b2 = (float)(b2 / a0);
    r.a1 = (float)(a1 / a0); r.a2 = (float)(a2 / a0);
    return r;
}

static BQ make_lp(double cutoff, double Q) {
    const double SR = 44100.0;
    double w0 = 2.0 * M_PI * cutoff / SR;
    double alpha = sin(w0) / (2.0 * Q);
    double c = cos(w0);
    double b0 = (1.0 - c) / 2.0, b1 = 1.0 - c, b2 = (1.0 - c) / 2.0;
    double a0 = 1.0 + alpha, a1 = -2.0 * c, a2 = 1.0 - alpha;
    BQ r;
    r.b0 = (float)(b0 / a0); r.b1 = (float)(b1 / a0); r.b2 = (float)(b2 / a0);
    r.a1 = (float)(a1 / a0); r.a2 = (float)(a2 / a0);
    return r;
}

static BQ make_hp(double cutoff, double Q) {
    const double SR = 44100.0;
    double w0 = 2.0 * M_PI * cutoff / SR;
    double alpha = sin(w0) / (2.0 * Q);
    double c = cos(w0);
    double b0 = (1.0 + c) / 2.0, b1 = -(1.0 + c), b2 = (1.0 + c) / 2.0;
    double a0 = 1.0 + alpha, a1 = -2.0 * c, a2 = 1.0 - alpha;
    BQ r;
    r.b0 = (float)(b0 / a0); r.b1 = (float)(b1 / a0); r.b2 = (float)(b2 / a0);
    r.a1 = (float)(a1 / a0); r.a2 = (float)(a2 / a0);
    return r;
}

extern "C" void kernel_launch(void* const* d_in, const int* in_sizes, int n_in,
                              void* d_out, int out_size, void* d_ws, size_t ws_size,
                              hipStream_t stream) {
    const float* x = (const float*)d_in[0];
    float* out = (float*)d_out;

    const int T = 441000;                 // time length (fixed by reference)
    int total = in_sizes[0];
    int B = total / T;                    // 32

    int chunksPerRow = (T + L_CHUNK - 1) / L_CHUNK;   // 1723
    int nThreads = B * chunksPerRow;                  // 55136

    BQ f1 = make_eq(1000.0, 6.0, 1.0);
    BQ f2 = make_lp(8000.0, 0.7071067811865476);
    BQ f3 = make_hp(300.0, 0.7071067811865476);

    int block = 64;   // 1 wave/block -> spread blocks across all 256 CUs
    int grid = (nThreads + block - 1) / block;
    hipLaunchKernelGGL(biquad3_kernel, dim3(grid), dim3(block), 0, stream,
                       x, out, T, chunksPerRow, nThreads, f1, f2, f3);
}